// Round 1
// 1102.554 us; speedup vs baseline: 1.1682x; 1.1682x over previous
//
#include <hip/hip_runtime.h>
#include <cstdint>
#include <cmath>

#define NN 8192
#define DD 512
#define KP1 31                      // k+1 with k=30
#define HALF_EDGES (NN * KP1)       // 253952

typedef float f2 __attribute__((ext_vector_type(2)));

// ---------------- Threefry-2x32-20, key = (0, 42) --------------------------
__device__ __forceinline__ uint32_t rotl32(uint32_t v, int s) {
  return (v << s) | (v >> (32 - s));
}

__device__ __forceinline__ void threefry2x32_42(uint32_t x0, uint32_t x1,
                                                uint32_t& o0, uint32_t& o1) {
  const uint32_t ks0 = 0u, ks1 = 42u;
  const uint32_t ks2 = 0x1BD11BDAu ^ ks0 ^ ks1;
  x0 += ks0; x1 += ks1;
  x0 += x1; x1 = rotl32(x1, 13); x1 ^= x0;
  x0 += x1; x1 = rotl32(x1, 15); x1 ^= x0;
  x0 += x1; x1 = rotl32(x1, 26); x1 ^= x0;
  x0 += x1; x1 = rotl32(x1, 6);  x1 ^= x0;
  x0 += ks1; x1 += ks2 + 1u;
  x0 += x1; x1 = rotl32(x1, 17); x1 ^= x0;
  x0 += x1; x1 = rotl32(x1, 29); x1 ^= x0;
  x0 += x1; x1 = rotl32(x1, 16); x1 ^= x0;
  x0 += x1; x1 = rotl32(x1, 24); x1 ^= x0;
  x0 += ks2; x1 += ks0 + 2u;
  x0 += x1; x1 = rotl32(x1, 13); x1 ^= x0;
  x0 += x1; x1 = rotl32(x1, 15); x1 ^= x0;
  x0 += x1; x1 = rotl32(x1, 26); x1 ^= x0;
  x0 += x1; x1 = rotl32(x1, 6);  x1 ^= x0;
  x0 += ks0; x1 += ks1 + 3u;
  x0 += x1; x1 = rotl32(x1, 17); x1 ^= x0;
  x0 += x1; x1 = rotl32(x1, 29); x1 ^= x0;
  x0 += x1; x1 = rotl32(x1, 16); x1 ^= x0;
  x0 += x1; x1 = rotl32(x1, 24); x1 ^= x0;
  x0 += ks1; x1 += ks2 + 4u;
  x0 += x1; x1 = rotl32(x1, 13); x1 ^= x0;
  x0 += x1; x1 = rotl32(x1, 15); x1 ^= x0;
  x0 += x1; x1 = rotl32(x1, 26); x1 ^= x0;
  x0 += x1; x1 = rotl32(x1, 6);  x1 ^= x0;
  x0 += ks2; x1 += ks0 + 5u;
  o0 = x0; o1 = x1;
}

__device__ __forceinline__ bool keep_edge(uint32_t e) {
  uint32_t y0, y1;
  threefry2x32_42(0u, e, y0, y1);
  uint32_t bits = y0 ^ y1;
  float u = __uint_as_float((bits >> 9) | 0x3f800000u) - 1.0f;
  return u < 0.9f;
}

// ---------------- K1: fp32 row norm (numpy pairwise tree) ------------------
__global__ __launch_bounds__(256) void rownorm_kernel(const float* __restrict__ x,
                                                      float* __restrict__ nrm) {
#pragma clang fp contract(off)
  __shared__ float rowbuf[16][DD];
  __shared__ float partial[16][4];
  int tid = threadIdx.x;
  int rowbase = blockIdx.x * 16;

  for (int p = 0; p < 8; ++p) {
    int f = tid + p * 256;
    int r = f >> 7, k4 = f & 127;
    *(float4*)(&rowbuf[r][k4 << 2]) =
        *(const float4*)(x + (size_t)(rowbase + r) * DD + (k4 << 2));
  }
  __syncthreads();
  if (tid < 64) {
    int r = tid >> 2, q = tid & 3;
    const float* s = &rowbuf[r][q * 128];
    float a0 = s[0]*s[0], a1 = s[1]*s[1], a2 = s[2]*s[2], a3 = s[3]*s[3];
    float a4 = s[4]*s[4], a5 = s[5]*s[5], a6 = s[6]*s[6], a7 = s[7]*s[7];
    for (int i = 8; i < 128; i += 8) {
      a0 += s[i+0]*s[i+0]; a1 += s[i+1]*s[i+1];
      a2 += s[i+2]*s[i+2]; a3 += s[i+3]*s[i+3];
      a4 += s[i+4]*s[i+4]; a5 += s[i+5]*s[i+5];
      a6 += s[i+6]*s[i+6]; a7 += s[i+7]*s[i+7];
    }
    partial[r][q] = ((a0 + a1) + (a2 + a3)) + ((a4 + a5) + (a6 + a7));
  }
  __syncthreads();
  if (tid < 16) {
    float S = (partial[tid][0] + partial[tid][1]) + (partial[tid][2] + partial[tid][3]);
    nrm[rowbase + tid] = sqrtf(S);
  }
}

// ---------------- K1b: xn = x / nrm (exact divide, done once) --------------
__global__ __launch_bounds__(256) void xnorm_kernel(const float* __restrict__ x,
                                                    const float* __restrict__ nrm,
                                                    float* __restrict__ xn) {
#pragma clang fp contract(off)
  int idx = blockIdx.x * 256 + threadIdx.x;   // float4 index, NN*128 total
  const float4* xv = (const float4*)x;
  float4* xo = (float4*)xn;
  float4 v = xv[idx];
  float n = nrm[idx >> 7];
  v.x = v.x / n; v.y = v.y / n; v.z = v.z / n; v.w = v.w / n;
  xo[idx] = v;
}

// ---------------- K2: upper-triangular 128x128 sim GEMM, packed-fp32 -------
// Compact launch: 2080 blocks, bid -> (by, bx) with bx >= by. sim is bitwise
// symmetric -> off-diag tiles written straight (direct) + transposed (LDS
// re-tile). Per-element rounding contract: sequential separate mul+add, k
// ascending. v_pk_mul_f32/v_pk_add_f32 preserve per-element IEEE rounding
// exactly (two independent f32 ops per instr) -> bitwise identical, half the
// VALU instructions. B tile stored k-major in LDS so column pairs are
// register-contiguous for the packed ops.
// LDS: As [128 rows][8 f4 slots] (16KB, slot-rotation swizzle) +
//      Bs [32 k][128 cols] (16KB, 8-col XOR swizzle by (k>>2)&3).
// 32KB/block -> 3-4 blocks/CU (was 64KB -> 2).
template <bool PRE>
__global__ __launch_bounds__(256, 2) void gemm_kernel(const float* __restrict__ x,
                                                      const float* __restrict__ nrm,
                                                      float* __restrict__ out) {
#pragma clang fp contract(off)
  // ---- triangular block index
  int bid = blockIdx.x;
  int by = (int)((129.0f - sqrtf(16641.0f - 8.0f * (float)bid)) * 0.5f);
  while (64 * by - (by * (by - 1)) / 2 > bid) --by;
  while (64 * (by + 1) - ((by + 1) * by) / 2 <= bid) ++by;
  const int bx = by + (bid - (64 * by - (by * (by - 1)) / 2));

  extern __shared__ char smem[];
  float4* AsF4 = (float4*)smem;            // [128][8] float4 = 16 KB
  float*  Bs   = (float*)(smem + 16384);   // [32][128] float = 16 KB

  const int tid = threadIdx.x;
  const int rb = by * 128;
  const int cb = bx * 128;
  const int m = tid & 7;        // k-slot (float4) within 32-k chunk
  const int g = tid >> 3;       // 0..31: staging row/col base

  float nA[4], nB[4];
  if (!PRE) {
    #pragma unroll
    for (int p = 0; p < 4; ++p) {
      nA[p] = nrm[rb + g + 32 * p];
      nB[p] = nrm[cb + g + 32 * p];
    }
  }

  const int lane = tid & 63, wave = tid >> 6;
  const int wr = wave >> 1, wc = wave & 1;
  const int lr = lane >> 3, lc = lane & 7;
  const int r0 = wr * 64 + lr * 8;     // 8 thread rows: r0..r0+7
  const int c0 = wc * 64 + lc * 8;     // 8 thread cols: c0..c0+7 (contiguous!)

  f2 acc[8][4];                        // acc[i][jp] = cols (c0+2jp, c0+2jp+1)
  #pragma unroll
  for (int i = 0; i < 8; ++i)
    #pragma unroll
    for (int jp = 0; jp < 4; ++jp) { acc[i][jp].x = 0.f; acc[i][jp].y = 0.f; }

  const float4* xv = (const float4*)x;

  // prologue: prefetch chunk 0 raw tiles into registers
  float4 ra[4], rbv[4];
  #pragma unroll
  for (int p = 0; p < 4; ++p) {
    int r = g + 32 * p;
    ra[p]  = xv[(size_t)(rb + r) * 128 + m];
    rbv[p] = xv[(size_t)(cb + r) * 128 + m];
  }

  for (int kc = 0; kc < 16; ++kc) {
    __syncthreads();                         // LDS consumers of prev chunk done
    #pragma unroll
    for (int p = 0; p < 4; ++p) {
      int r = g + 32 * p;
      float4 va = ra[p];
      if (!PRE) {
        va.x = va.x / nA[p]; va.y = va.y / nA[p];
        va.z = va.z / nA[p]; va.w = va.w / nA[p];
      }
      AsF4[r * 8 + ((m + (r >> 3)) & 7)] = va;
      float4 vb = rbv[p];
      if (!PRE) {
        vb.x = vb.x / nB[p]; vb.y = vb.y / nB[p];
        vb.z = vb.z / nB[p]; vb.w = vb.w / nB[p];
      }
      // transpose to k-major: Bs[k][col ^ ((k>>2)&3)<<3], k = 4m+kk
      float* bp = Bs + (4 * m) * 128 + (r ^ ((m & 3) << 3));
      bp[0]   = vb.x;
      bp[128] = vb.y;
      bp[256] = vb.z;
      bp[384] = vb.w;
    }
    __syncthreads();
    if (kc < 15) {                           // prefetch next chunk (overlaps compute)
      #pragma unroll
      for (int p = 0; p < 4; ++p) {
        int r = g + 32 * p;
        ra[p]  = xv[(size_t)(rb + r) * 128 + (kc + 1) * 8 + m];
        rbv[p] = xv[(size_t)(cb + r) * 128 + (kc + 1) * 8 + m];
      }
    }

    #pragma unroll 2
    for (int k4 = 0; k4 < 8; ++k4) {
      float4 av[8];
      const int tA = (k4 + (r0 >> 3)) & 7;   // distinct per lr -> conflict-free
      #pragma unroll
      for (int i = 0; i < 8; ++i) av[i] = AsF4[(r0 + i) * 8 + tA];
      float4 b01[8];                         // b01[2kk]=cols c0..c0+3, b01[2kk+1]=c0+4..c0+7
      const int csw = c0 ^ ((k4 & 3) << 3);
      #pragma unroll
      for (int kk = 0; kk < 4; ++kk) {
        const float* bp = Bs + (4 * k4 + kk) * 128 + csw;
        b01[2 * kk]     = *(const float4*)(bp);
        b01[2 * kk + 1] = *(const float4*)(bp + 4);
      }
      #pragma unroll
      for (int kk = 0; kk < 4; ++kk) {
        f2 bb0 = {b01[2 * kk].x,     b01[2 * kk].y};
        f2 bb1 = {b01[2 * kk].z,     b01[2 * kk].w};
        f2 bb2 = {b01[2 * kk + 1].x, b01[2 * kk + 1].y};
        f2 bb3 = {b01[2 * kk + 1].z, b01[2 * kk + 1].w};
        #pragma unroll
        for (int i = 0; i < 8; ++i) {
          float a = ((const float*)&av[i])[kk];
          f2 t0 = a * bb0; acc[i][0] = acc[i][0] + t0;   // v_pk_mul + v_pk_add
          f2 t1 = a * bb1; acc[i][1] = acc[i][1] + t1;
          f2 t2 = a * bb2; acc[i][2] = acc[i][2] + t2;
          f2 t3 = a * bb3; acc[i][3] = acc[i][3] + t3;
        }
      }
    }
  }

  // ---- epilogue -----------------------------------------------------------
  float4* outv = (float4*)out;

  // straight tile: direct from registers (thread cols are contiguous)
  #pragma unroll
  for (int i = 0; i < 8; ++i) {
    #pragma unroll
    for (int h = 0; h < 2; ++h) {
      float4 o;
      o.x = acc[i][2 * h].x;     o.y = acc[i][2 * h].y;
      o.z = acc[i][2 * h + 1].x; o.w = acc[i][2 * h + 1].y;
      outv[(size_t)(rb + r0 + i) * 2048 + ((cb + c0) >> 2) + h] = o;
    }
  }

  // transposed mirror via LDS re-tile, 4 quarters of 32 rows (stride 130,
  // f2 stores -> 8B aligned, <=4-way)
  if (rb != cb) {
    float* Cs = (float*)smem;                // 32*130*4 = 16.6 KB, reuse
    #pragma unroll 1
    for (int q = 0; q < 4; ++q) {
      __syncthreads();
      if (wr == (q >> 1) && (lr >> 2) == (q & 1)) {
        const int rB = (lr & 3) * 8;
        #pragma unroll
        for (int i = 0; i < 8; ++i) {
          #pragma unroll
          for (int jp = 0; jp < 4; ++jp)
            *(f2*)(Cs + (rB + i) * 130 + wc * 64 + lc * 8 + 2 * jp) = acc[i][jp];
        }
      }
      __syncthreads();
      #pragma unroll
      for (int q2 = 0; q2 < 4; ++q2) {
        int f = tid + q2 * 256;              // 0..1023
        int c = f >> 3, t4 = f & 7;          // col 0..127, 4-row group 0..7
        float4 o;
        o.x = Cs[(4 * t4 + 0) * 130 + c];
        o.y = Cs[(4 * t4 + 1) * 130 + c];
        o.z = Cs[(4 * t4 + 2) * 130 + c];
        o.w = Cs[(4 * t4 + 3) * 130 + c];
        outv[(size_t)(cb + c) * 2048 + ((rb + q * 32) >> 2) + t4] = o;
      }
    }
  }
}

// ---------------- K3: per-row top-31, lane-registered O(1) insertion -------
__global__ __launch_bounds__(256) void topk_kernel(const float* __restrict__ sim,
                                                   float* __restrict__ vals,
                                                   int* __restrict__ inds) {
  const int w = threadIdx.x >> 6;
  const int lane = threadIdx.x & 63;
  const int row = blockIdx.x * 4 + w;

  float kval = -1e30f;
  int   kidx = 0;
  float kmin = -1e30f;

  const float* srow = sim + (size_t)row * NN;
  for (int grp = 0; grp < NN / 64; ++grp) {
    float v = srow[grp * 64 + lane];
    unsigned long long mask = __ballot(v > kmin);
    while (mask) {
      int src = __builtin_ctzll(mask);
      mask &= mask - 1;
      float vv = __shfl(v, src, 64);          // wave-uniform candidate
      if (vv > kmin) {
        int cc = grp * 64 + src;
        unsigned long long ge = __ballot(kval >= vv) & 0x7FFFFFFFull;
        int pos = __popcll(ge);               // slots strictly before vv
        float upv = __shfl_up(kval, 1, 64);
        int   upi = __shfl_up(kidx, 1, 64);
        if (lane < KP1) {
          if (lane == pos) { kval = vv; kidx = cc; }
          else if (lane > pos) { kval = upv; kidx = upi; }
        }
        kmin = __shfl(kval, KP1 - 1, 64);
      }
    }
  }
  if (lane < KP1) {
    vals[(size_t)row * KP1 + lane] = kval;
    inds[row * KP1 + lane] = kidx;
  }
}

// ---------------- K4: degree mass (norm_row + norm_col) --------------------
__global__ __launch_bounds__(256) void norm_kernel(const float* __restrict__ vals,
                                                   const int* __restrict__ inds,
                                                   float* __restrict__ norm) {
  int i = blockIdx.x * blockDim.x + threadIdx.x;
  if (i >= NN) return;
  float s = 0.f;
  for (int t = 0; t < KP1; ++t) {
    float v = vals[i * KP1 + t];
    s += v;
    atomicAdd(&norm[inds[i * KP1 + t]], v);
  }
  atomicAdd(&norm[i], s);
}

// ---------------- K5: normalize + relu + threefry dropout + scatter --------
__global__ __launch_bounds__(256) void scatter_kernel(const float* __restrict__ vals,
                                                      const int* __restrict__ inds,
                                                      const float* __restrict__ norm,
                                                      float* __restrict__ out) {
  int e = blockIdx.x * blockDim.x + threadIdx.x;
  if (e >= HALF_EDGES) return;
  int i = e / KP1;
  int c = inds[e];
  float v = vals[e];
  float nv = v * (1.0f / sqrtf(norm[i])) * (1.0f / sqrtf(norm[c]));
  if (isnan(nv)) nv = 0.f;
  nv = fmaxf(nv, 0.f);
  float scaled = nv / 0.9f;
  if (keep_edge((uint32_t)e))
    atomicAdd(out + (size_t)i * NN + c, scaled);
  if (keep_edge((uint32_t)(e + HALF_EDGES)))
    atomicAdd(out + (size_t)c * NN + i, scaled);
}

// ---------------------------------------------------------------------------
extern "C" void kernel_launch(void* const* d_in, const int* in_sizes, int n_in,
                              void* d_out, int out_size, void* d_ws, size_t ws_size,
                              hipStream_t stream) {
  (void)in_sizes; (void)n_in;
  const float* x = (const float*)d_in[0];
  float* out = (float*)d_out;

  // ws layout: first 2 MiB exactly = nrm + vals + inds + norm (proven budget);
  // optional xn (16 MiB) appended only if the workspace is big enough.
  float* nrm  = (float*)d_ws;                  // 8192 floats
  float* vals = nrm + NN;                      // 253952 floats
  int*   inds = (int*)(vals + HALF_EDGES);     // 253952 ints
  float* norm = (float*)(inds + HALF_EDGES);   // 8192 floats
  float* xn   = (float*)((char*)d_ws + (size_t)(2 * 1024 * 1024));
  const bool pre = ws_size >= (size_t)(2 * 1024 * 1024) + (size_t)NN * DD * 4;

  hipLaunchKernelGGL(rownorm_kernel, dim3(NN / 16), dim3(256), 0, stream, x, nrm);
  // sims -> d_out (256 MB scratch, consumed by topk before the final memset)
  if (pre) {
    hipLaunchKernelGGL(xnorm_kernel, dim3(NN * DD / 4 / 256), dim3(256), 0, stream,
                       x, nrm, xn);
    hipLaunchKernelGGL((gemm_kernel<true>), dim3(2080), dim3(256), 32768, stream,
                       xn, (const float*)nullptr, out);
  } else {
    hipLaunchKernelGGL((gemm_kernel<false>), dim3(2080), dim3(256), 32768, stream,
                       x, nrm, out);
  }
  hipLaunchKernelGGL(topk_kernel, dim3(NN / 4), dim3(256), 0, stream,
                     out, vals, inds);
  hipMemsetAsync(norm, 0, NN * sizeof(float), stream);
  hipLaunchKernelGGL(norm_kernel, dim3((NN + 255) / 256), dim3(256), 0, stream,
                     vals, inds, norm);
  hipMemsetAsync(d_out, 0, (size_t)out_size * sizeof(float), stream);
  hipLaunchKernelGGL(scatter_kernel, dim3((HALF_EDGES + 255) / 256), dim3(256), 0, stream,
                     vals, inds, norm, out);
}